// Round 10
// baseline (3867.841 us; speedup 1.0000x reference)
//
#include <hip/hip_runtime.h>
#include <stdint.h>

// BiLSTM-CRF forward on MI355X.
// R19 = R18 lstm (552 us proven: 32 WGs x 4 batches, permlane32/16 cell
//       distribution, K=128 scaled MFMA, exp2 gate math, soft barrier)
//     + xg_gemm FUSED into the same launch as producer blocks (32 lstm blocks +
//       4096 xg blocks, one kernel): xg runs on the 224 idle CUs while lstm
//       consumes chunks in timestep order via per-(d,g16,32-step-chunk) flags
//       (8 producer WGs per chunk; threadfence+agent-scope atomics; tid0 spin
//       with s_sleep). Deadlock-free: lstm holds <=32 CUs, xg has no deps.
typedef unsigned short u16;
typedef __attribute__((ext_vector_type(4))) float f32x4;
typedef __attribute__((ext_vector_type(8))) short short8;
typedef __attribute__((ext_vector_type(8))) int v8i;

#define OFF_BIAS   ((size_t)0)           // 2048*4
#define OFF_WFRAG  ((size_t)8192)        // 512 KB fp8 w_hh frags (K=128 grouping)
#define OFF_HHIST  ((size_t)1048576)     // [2][64][512][256] u16 = 32 MB
#define OFF_FEATS  ((size_t)34603008)    // 32768*9*4
#define OFF_XG     ((size_t)37748736)    // [2*16 grp][512 s][512 tid][8 u16] = 128 MB
#define OFF_XBF    ((size_t)171966464)   // [32768][256] u16 = 16 MB (gathered x, bf16)
#define OFF_WBF    ((size_t)188743680)   // [2][1024][256] u16 = 1 MB (w_ih, bf16)
#define OFF_FLAGS  ((size_t)189792256)   // [2][16][16] int = 2 KB chunk flags

__device__ __forceinline__ float bf2f(u16 h) {
  union { uint32_t u; float f; } v; v.u = ((uint32_t)h) << 16; return v.f;
}
__device__ __forceinline__ float bfh(uint32_t wrd, int hh) {
  return bf2f((u16)(wrd >> (16 * hh)));
}
__device__ __forceinline__ uint32_t cvtpk_bf16(float lo, float hi) {
  uint32_t r;
  asm("v_cvt_pk_bf16_f32 %0, %1, %2" : "=v"(r) : "v"(lo), "v"(hi));
  return r;
}
__device__ __forceinline__ uint32_t f2u(float f) {
  union { float f; uint32_t u; } v; v.f = f; return v.u;
}
__device__ __forceinline__ float u2f(uint32_t u) {
  union { uint32_t u; float f; } v; v.u = u; return v.f;
}
// permlane32_swap: result0 = {a[0:31] in lanes 0-31, b[0:31] in lanes 32-63},
// lane-correspondent (VALU pipe). HW-verified R17/R18 (absmax 0).
__device__ __forceinline__ float pl32_lo(float a, float b) {
  auto pr = __builtin_amdgcn_permlane32_swap(f2u(a), f2u(b), false, false);
  return u2f(((const uint32_t*)&pr)[0]);
}
__device__ __forceinline__ float pl32_hi(float a, float b) {
  auto pr = __builtin_amdgcn_permlane32_swap(f2u(a), f2u(b), false, false);
  return u2f(((const uint32_t*)&pr)[1]);
}
// permlane16_swap(x,x) result0: even 16-lane rows keep x, odd rows receive the
// even row below. HW-verified R18 (absmax 0).
__device__ __forceinline__ float pl16_bcast(float x) {
#if __has_builtin(__builtin_amdgcn_permlane16_swap)
  auto pr = __builtin_amdgcn_permlane16_swap(f2u(x), f2u(x), false, false);
  return u2f(((const uint32_t*)&pr)[0]);
#else
  uint32_t a = f2u(x), b = f2u(x);
  asm("v_permlane16_swap_b32 %0, %1" : "+v"(a), "+v"(b));
  return u2f(a);
#endif
}
__device__ __forceinline__ short8 pack8(f32x4 a, f32x4 b) {
  union { short8 s; uint32_t u[4]; } r;
  r.u[0] = cvtpk_bf16(a[0], a[1]);
  r.u[1] = cvtpk_bf16(a[2], a[3]);
  r.u[2] = cvtpk_bf16(b[0], b[1]);
  r.u[3] = cvtpk_bf16(b[2], b[3]);
  return r.s;
}

// ---- combined input-gate bias ----
__global__ void bias_kernel(const float* __restrict__ bihf, const float* __restrict__ bhhf,
                            const float* __restrict__ bihb, const float* __restrict__ bhhb,
                            float* __restrict__ bias) {
  int n = blockIdx.x * 256 + threadIdx.x;
  if (n < 1024) bias[n] = bihf[n] + bhhf[n];
  else          bias[n] = bihb[n - 1024] + bhhb[n - 1024];
}

// ---- one-time bf16 materialization: x = emb[sent] and w_ih, both as u16 ----
__global__ void __launch_bounds__(256) pack_kernel(
    const int* __restrict__ sent, const float* __restrict__ emb,
    const float* __restrict__ wihf, const float* __restrict__ wihb,
    u16* __restrict__ xbf, u16* __restrict__ wbf)
{
  int gid = blockIdx.x * 256 + threadIdx.x;
  if (gid < 1048576) {                       // x: 32768 tokens x 256 cols / 8
    const int tok = gid >> 5;
    const int c8 = (gid & 31) * 8;
    const int t = sent[tok];
    const float* src = emb + (size_t)t * 256 + c8;
    f32x4 a0 = *(const f32x4*)(src);
    f32x4 a1 = *(const f32x4*)(src + 4);
    *(short8*)(xbf + (size_t)tok * 256 + c8) = pack8(a0, a1);
  } else if (gid < 1114112) {                // w_ih: 2 x 1024 x 256 / 8
    const int g2 = gid - 1048576;
    const int row = g2 >> 5;                 // 0..2047 = d*1024 + r
    const int c8 = (g2 & 31) * 8;
    const float* W = (row < 1024) ? wihf : wihb;
    const float* src = W + (size_t)(row & 1023) * 256 + c8;
    f32x4 a0 = *(const f32x4*)(src);
    f32x4 a1 = *(const f32x4*)(src + 4);
    *(short8*)(wbf + (size_t)row * 256 + c8) = pack8(a0, a1);
  }
}

// ---- w_hh -> fp8 e4m3 B-fragments (x16 scale), K-order permuted by pi ----
__global__ void wfrag_prep_kernel(const float* __restrict__ whhf,
                                  const float* __restrict__ whhb,
                                  uint8_t* __restrict__ wfrag) {
  int gid = blockIdx.x * 256 + threadIdx.x;   // 0..32767
  const int l    = gid & 63;
  const int kt   = (gid >> 6) & 7;
  const int gate = (gid >> 9) & 3;
  const int ubi  = (gid >> 11) & 1;
  const int w    = (gid >> 12) & 7;
  const int d    = (gid >> 15) & 1;
  const float* W = d ? whhb : whhf;
  const int n = l & 15, q = l >> 4;
  const int row = gate * 256 + w * 32 + ubi * 16 + n;
  uint32_t out[2] = {0u, 0u};
  #pragma unroll
  for (int jj = 0; jj < 4; ++jj) {
    const int k0 = kt * 32 + q * 8 + jj * 2;
    const int k1 = k0 + 1;
    const int u0 = (k0 >> 5) * 32 + (k0 & 1) * 16 + ((k0 & 31) >> 1);
    const int u1 = (k1 >> 5) * 32 + (k1 & 1) * 16 + ((k1 & 31) >> 1);
    const float f0 = W[(size_t)row * 256 + u0] * 16.0f;
    const float f1 = W[(size_t)row * 256 + u1] * 16.0f;
    const int pk = __builtin_amdgcn_cvt_pk_fp8_f32(f0, f1, 0, false);
    out[jj >> 1] |= (uint32_t)(pk & 0xffff) << (16 * (jj & 1));
  }
  const int p = kt >> 2, cc = kt & 3;
  const size_t addr =
      ((((size_t)((d * 8 + w) * 2 + ubi) * 4 + gate) * 2 + p) * 64 + l) * 32 + (size_t)cc * 8;
  *(uint2*)(wfrag + addr) = make_uint2(out[0], out[1]);
}

// ---- one LSTM timestep (4-batch WG, R18 verbatim) ----
template<int CB, int PW>
__device__ __forceinline__ void lstm_step(
    int T, int d, int l, int q, int n, int w,
    const v8i (&wvr)[2][4][2], float (&cst)[2],
    uint4& X0,
    uint8_t* hx, const u16* xsl, u16* hhb)
{
  const int t_eff = d ? (511 - T) : T;

  int tn = T + 2; if (tn > 511) tn = 511;
  const int sn = d ? (511 - tn) : tn;
  const uint4 P0 = *(const uint4*)(xsl + (size_t)sn * 4096);

  const uint8_t* hr = hx + CB * 4224 + (l & 15) * 264 + q * 8;
  const int2 b0 = *(const int2*)(hr +   0);
  const int2 b1 = *(const int2*)(hr +  32);
  const int2 b2 = *(const int2*)(hr +  64);
  const int2 b3 = *(const int2*)(hr +  96);
  const int2 b4 = *(const int2*)(hr + 128);
  const int2 b5 = *(const int2*)(hr + 160);
  const int2 b6 = *(const int2*)(hr + 192);
  const int2 b7 = *(const int2*)(hr + 224);
  const v8i A0 = (v8i){b0.x, b0.y, b1.x, b1.y, b2.x, b2.y, b3.x, b3.y};
  const v8i A1 = (v8i){b4.x, b4.y, b5.x, b5.y, b6.x, b6.y, b7.x, b7.y};

  f32x4 acc[2][4];
  #pragma unroll
  for (int ubi = 0; ubi < 2; ++ubi)
    #pragma unroll
    for (int gate = 0; gate < 4; ++gate) {
      f32x4 a = (f32x4){0.f, 0.f, 0.f, 0.f};
      a = __builtin_amdgcn_mfma_scale_f32_16x16x128_f8f6f4(
              A0, wvr[ubi][gate][0], a, 0, 0, 0, 0x7f7f7f7f, 0, 0x7f7f7f7f);
      a = __builtin_amdgcn_mfma_scale_f32_16x16x128_f8f6f4(
              A1, wvr[ubi][gate][1], a, 0, 0, 0, 0x7f7f7f7f, 0, 0x7f7f7f7f);
      acc[ubi][gate] = a;
    }

  // stage 1 (ubi split), stage 2 (r-pair split) -- both VALU-pipe permlanes.
  f32x4 accs[4];
  #pragma unroll
  for (int gate = 0; gate < 4; ++gate)
    #pragma unroll
    for (int r = 0; r < 4; ++r)
      accs[gate][r] = pl32_lo(acc[0][gate][r], acc[1][gate][r]);

  float a2[4][2];
  #pragma unroll
  for (int gate = 0; gate < 4; ++gate)
    #pragma unroll
    for (int j = 0; j < 2; ++j) {
      const float t1 = pl16_bcast(accs[gate][2 + j]);
      a2[gate][j] = (q & 1) ? t1 : accs[gate][j];
    }

  const float Sm = -0.0056355275f;   // -log2e/256
  const float Sg =  0.0112710550f;   // +2*log2e/256
  const float K2 =  2.8853900818f;   // 2*log2e
  float hval[2];
  #pragma unroll
  for (int j = 0; j < 2; ++j) {
    const float argi = fmaf(a2[0][j], Sm, bfh(X0.x, j));
    const float argf = fmaf(a2[1][j], Sm, bfh(X0.y, j));
    const float argg = fmaf(a2[2][j], Sg, bfh(X0.z, j));
    const float argo = fmaf(a2[3][j], Sm, bfh(X0.w, j));
    const float Ei = __builtin_amdgcn_exp2f(argi);
    const float Ef = __builtin_amdgcn_exp2f(argf);
    const float Eg = __builtin_amdgcn_exp2f(argg);
    const float Eo = __builtin_amdgcn_exp2f(argo);
    const float pf_ = 1.0f + Ef, pi_ = 1.0f + Ei, pg_ = 1.0f + Eg;
    const float P  = pi_ * pg_;
    const float rD = __builtin_amdgcn_rcpf(P * pf_);
    const float num = fmaf(cst[j], P, fmaf(Eg, pf_, -pf_));
    const float c   = num * rD;
    cst[j] = c;
    const float E2 = __builtin_amdgcn_exp2f(c * K2);
    const float rQ = __builtin_amdgcn_rcpf((1.0f + E2) * (1.0f + Eo));
    hval[j] = fmaf(E2, rQ, -rQ);
  }

  const float ho0 = pl32_hi(hval[0], hval[0]);
  const float ho1 = pl32_hi(hval[1], hval[1]);
  if (q < 2) {
    uint8_t* hw = hx + PW * 4224 + w * 32 + 2 * n;
    const int m0 = (q & 1) * 2;
    const int pk0 = __builtin_amdgcn_cvt_pk_fp8_f32(hval[0] * 16.0f, ho0 * 16.0f, 0, false);
    const int pk1 = __builtin_amdgcn_cvt_pk_fp8_f32(hval[1] * 16.0f, ho1 * 16.0f, 0, false);
    *(u16*)(hw + (m0)     * 264) = (u16)(pk0 & 0xffff);
    *(u16*)(hw + (m0 + 1) * 264) = (u16)(pk1 & 0xffff);
  }

  asm volatile("s_waitcnt lgkmcnt(0)" ::: "memory");
  __builtin_amdgcn_s_barrier();
  __builtin_amdgcn_sched_barrier(0);

  {
    u16* hhs = hhb + (size_t)t_eff * 256;
    const uint32_t pb = cvtpk_bf16(hval[0], hval[1]);
    const int m0 = (q & 1) * 2;
    hhs[(size_t)(m0)     * 131072] = (u16)(pb & 0xffffu);
    hhs[(size_t)(m0 + 1) * 131072] = (u16)(pb >> 16);
  }

  X0 = P0;
}

// ---- fused producer/consumer kernel ----
// blocks 0..31  : LSTM role (dir(2) x batch-group(16 of 4)), R18 structure +
//                 per-32-step chunk waits on flags.
// blocks 32..4127: xg GEMM role (x = d,u0 ; y = g,qb,s0), 512-thread staging,
//                 256-thread MFMA/epilogue, flag publish per (d,g16,chunk).
__global__ void __launch_bounds__(512, 4) fused_xg_lstm_kernel(
    const u16* __restrict__ xbf, const u16* __restrict__ wbf,
    const float* __restrict__ bias, u16* __restrict__ xgf,
    const uint8_t* __restrict__ wfrag, u16* __restrict__ hhist,
    int* __restrict__ flags)
{
  extern __shared__ char smem[];           // 70656 B, xg role only
  __shared__ uint8_t hx[2 * 16 * 264];     // lstm role only

  const int bid = blockIdx.x;
  const int tid = threadIdx.x;

  if (bid < 32) {
    // ================= LSTM role =================
    const int d = bid >> 4, g16 = bid & 15;
    const int w = tid >> 6, l = tid & 63;
    const int n = l & 15, q = l >> 4;

    v8i wvr[2][4][2];
    {
      const uint8_t* wb = wfrag + (size_t)(d * 8 + w) * 32768;
      #pragma unroll
      for (int ubi = 0; ubi < 2; ++ubi)
        #pragma unroll
        for (int gate = 0; gate < 4; ++gate)
          #pragma unroll
          for (int p = 0; p < 2; ++p) {
            const uint8_t* src = wb + ((size_t)(((ubi * 4 + gate) * 2 + p) * 64 + l)) * 32;
            const uint4 lo = *(const uint4*)(src);
            const uint4 hi = *(const uint4*)(src + 16);
            wvr[ubi][gate][p] = (v8i){(int)lo.x, (int)lo.y, (int)lo.z, (int)lo.w,
                                      (int)hi.x, (int)hi.y, (int)hi.z, (int)hi.w};
          }
    }

    for (int i = tid; i < 2112; i += 512) ((uint32_t*)hx)[i] = 0u;

    const u16* xsl = xgf + (size_t)(d * 16 + g16) * 2097152 + (size_t)tid * 8;
    float cst[2] = {};
    u16* hhb = hhist + ((size_t)(d * 64 + g16 * 4) * 512) * 256 + (w * 32 + (q >> 1) * 16 + n);
    int* flagrow = flags + (d * 16 + g16) * 16;

    // initial chunk wait (covers preload s(0),s(1) and first prefetches)
    int last_c = d ? 15 : 0;
    if (tid == 0) {
      while (__hip_atomic_load(&flagrow[last_c], __ATOMIC_ACQUIRE,
                               __HIP_MEMORY_SCOPE_AGENT) < 8)
        __builtin_amdgcn_s_sleep(8);
    }
    __syncthreads();
    __threadfence();

    uint4 X0, Y0;
    X0 = *(const uint4*)(xsl + (size_t)(d ? 511 : 0) * 4096);
    Y0 = *(const uint4*)(xsl + (size_t)(d ? 510 : 1) * 4096);
    __syncthreads();

    for (int tt = 0; tt < 512; tt += 2) {
      int sa = tt + 3; if (sa > 511) sa = 511;
      const int c = (d ? (511 - sa) : sa) >> 5;
      if (c != last_c) {
        if (tid == 0) {
          while (__hip_atomic_load(&flagrow[c], __ATOMIC_ACQUIRE,
                                   __HIP_MEMORY_SCOPE_AGENT) < 8)
            __builtin_amdgcn_s_sleep(8);
        }
        __syncthreads();
        __threadfence();
        last_c = c;
      }
      lstm_step<0, 1>(tt,     d, l, q, n, w, wvr, cst, X0, hx, xsl, hhb);
      lstm_step<1, 0>(tt + 1, d, l, q, n, w, wvr, cst, Y0, hx, xsl, hhb);
    }
    return;
  }

  // ================= xg GEMM role =================
  const int e = bid - 32;
  const int x = e & 15, y = e >> 4;
  const int d  = x >> 3, u0 = (x & 7) * 32;
  const int g  = y >> 6, qb = (y >> 4) & 3, s0 = (y & 15) * 32;

  u16*   Al    = (u16*)smem;             // [128][136]
  u16*   Bl    = (u16*)(smem + 34816);   // [128][136]
  float* biasl = (float*)(smem + 69632); // [128]

  if (tid < 128)
    biasl[tid] = bias[d * 1024 + (tid >> 5) * 256 + u0 + (tid & 31)];
  __syncthreads();

  f32x4 acc[4][4];
  #pragma unroll
  for (int i = 0; i < 4; ++i)
    #pragma unroll
    for (int j = 0; j < 4; ++j) acc[i][j] = (f32x4){0.f, 0.f, 0.f, 0.f};

  // staging coords (all 512 threads; quarter-row each)
  const int rr = tid >> 2, c0q = (tid & 3) * 32;
  const int xrow = (g * 16 + qb * 4 + (rr & 3)) * 512 + s0 + (rr >> 2);
  const int wrow = d * 1024 + (rr >> 5) * 256 + u0 + (rr & 31);

  // mfma coords (tid < 256 only)
  const int wv = tid >> 6, l = tid & 63;
  const int mh = ((wv & 3) >> 1) * 64, nh = (wv & 1) * 64;
  const int fr = l & 15, fq = l >> 4;

  for (int kc = 0; kc < 2; ++kc) {
    const int k0 = kc * 128;
    const u16* as = xbf + (size_t)xrow * 256 + k0 + c0q;
    const u16* bs = wbf + (size_t)wrow * 256 + k0 + c0q;
    u16* adst = Al + rr * 136 + c0q;
    u16* bdst = Bl + rr * 136 + c0q;
    #pragma unroll
    for (int gdx = 0; gdx < 4; ++gdx) {
      *(short8*)(adst + gdx * 8) = *(const short8*)(as + gdx * 8);
      *(short8*)(bdst + gdx * 8) = *(const short8*)(bs + gdx * 8);
    }
    __syncthreads();
    if (tid < 256) {
      #pragma unroll
      for (int ks = 0; ks < 4; ++ks) {
        short8 af[4], bfr[4];
        #pragma unroll
        for (int i = 0; i < 4; ++i)
          af[i] = *(const short8*)(Al + (mh + i * 16 + fr) * 136 + ks * 32 + fq * 8);
        #pragma unroll
        for (int j = 0; j < 4; ++j)
          bfr[j] = *(const short8*)(Bl + (nh + j * 16 + fr) * 136 + ks * 32 + fq * 8);
        #pragma unroll
        for (int i = 0; i < 4; ++i)
          #pragma unroll
          for (int j = 0; j < 4; ++j)
            acc[i][j] = __builtin_amdgcn_mfma_f32_16x16x32_bf16(af[i], bfr[j], acc[i][j], 0, 0, 0);
      }
    }
    __syncthreads();
  }

  if (tid < 256) {
    const float LOG2E = 1.4426950408889634f;
    const int g0 = nh >> 5;
    const float sA = (g0 == 2) ? (2.0f * LOG2E) : (-LOG2E);
    const int mh4 = mh >> 2;
    const int g16 = g * 4 + qb;
    u16* xbase = xgf + (size_t)(d * 16 + g16) * 2097152;
    #pragma unroll
    for (int i = 0; i < 4; ++i) {
      const int s = s0 + mh4 + i * 4 + fq;
      #pragma unroll
      for (int nsub = 0; nsub < 2; ++nsub) {
        const int cA = nh + nsub * 16 + fr, cB = nh + (nsub + 2) * 16 + fr;
        float vA[4], vB[4];
        #pragma unroll
        for (int r = 0; r < 4; ++r) {
          vA[r] = (acc[i][nsub][r] + biasl[cA]) * sA;
          vB[r] = (acc[i][nsub + 2][r] + biasl[cB]) * (-LOG2E);
        }
        #pragma unroll
        for (int p = 0; p < 2; ++p) {
          uint2 sv;
          sv.x = cvtpk_bf16(vA[p * 2], vA[p * 2 + 1]);
          sv.y = cvtpk_bf16(vB[p * 2], vB[p * 2 + 1]);
          const int tid2 = (u0 >> 5) * 64 + ((nsub << 1) | p) * 16 + fr;
          *(uint2*)(xbase + (size_t)s * 4096 + tid2 * 8 + g0 * 2) = sv;
        }
      }
    }
  }

  // publish: all stores drained to agent scope, then one count per WG.
  __threadfence();
  __syncthreads();
  if (tid == 0)
    __hip_atomic_fetch_add(&flags[((d * 16 + (g * 4 + qb)) * 16) + (y & 15)], 1,
                           __ATOMIC_RELEASE, __HIP_MEMORY_SCOPE_AGENT);
}

// ---- feats = [hf|hb] @ w_out^T + b_out ----
__global__ void __launch_bounds__(256) proj_kernel(
    const u16* __restrict__ hhist, const float* __restrict__ w_out,
    const float* __restrict__ b_out, float* __restrict__ feats)
{
  __shared__ float wsm[9 * 512];
  __shared__ float bsm[9];
  const int tid = threadIdx.x;
  for (int i = tid; i < 4608; i += 256) wsm[i] = w_out[i];
  if (tid < 9) bsm[tid] = b_out[tid];
  __syncthreads();

  const int wv = tid >> 6, l = tid & 63;
  const int gw = blockIdx.x * 4 + wv;
  const int jb = l * 8;
  const int dd = jb >> 8;
  const int jloc = jb & 255;

  for (int qq = 0; qq < 8; ++qq) {
    const int pos = gw * 8 + qq;
    const int b = pos >> 9, s = pos & 511;
    const u16* hp = hhist + ((size_t)(dd * 64 + b) * 512 + s) * 256 + jloc;
    short8 hv8 = *(const short8*)hp;
    float hf[8];
    #pragma unroll
    for (int j = 0; j < 8; ++j) hf[j] = bf2f((u16)hv8[j]);
    float pt[9];
    #pragma unroll
    for (int tg2 = 0; tg2 < 9; ++tg2) {
      const float* wr = wsm + tg2 * 512 + jb;
      float a = 0.f;
      #pragma unroll
      for (int j = 0; j < 8; ++j) a = fmaf(hf[j], wr[j], a);
      pt[tg2] = a;
    }
    #pragma unroll
    for (int tg2 = 0; tg2 < 9; ++tg2)
      #pragma unroll
      for (int off = 32; off; off >>= 1)
        pt[tg2] += __shfl_xor(pt[tg2], off, 64);
    if (l == 0) {
      float* fo = feats + (size_t)pos * 9;
      #pragma unroll
      for (int tg2 = 0; tg2 < 9; ++tg2) fo[tg2] = pt[tg2] + bsm[tg2];
    }
  }
}

// ---- CRF NLL ----
__global__ void __launch_bounds__(64) crf_kernel(
    const float* __restrict__ feats, const int* __restrict__ tags,
    const float* __restrict__ strans, const float* __restrict__ etrans,
    const float* __restrict__ trans, float* out)
{
  __shared__ float em[512 * 9];
  __shared__ float tr[81];
  __shared__ int   tg[512];
  const int b = blockIdx.x, l = threadIdx.x;
  const float* fb = feats + (size_t)b * 512 * 9;
  for (int i = l; i < 4608; i += 64) em[i] = fb[i];
  for (int i = l; i < 512; i += 64) tg[i] = tags[b * 512 + i];
  if (l < 81) tr[l] = trans[l];
  __syncthreads();

  float sc = 0.f;
  for (int s = 1 + l; s < 512; s += 64)
    sc += tr[tg[s - 1] * 9 + tg[s]] + em[s * 9 + tg[s]];
  #pragma unroll
  for (int off = 32; off; off >>= 1) sc += __shfl_xor(sc, off, 64);
  const float score = sc + strans[tg[0]] + em[tg[0]] + etrans[tg[511]];

  const int jj = (l < 9) ? l : 0;
  float al = (l < 9) ? (strans[l] + em[l]) : -1e30f;
  for (int t = 1; t < 512; ++t) {
    float ai[9];
    #pragma unroll
    for (int i = 0; i < 9; ++i) ai[i] = __shfl(al, i, 64);
    float m = ai[0];
    #pragma unroll
    for (int i = 1; i < 9; ++i) m = fmaxf(m, ai[i]);
    float ssum = 0.f;
    #pragma unroll
    for (int i = 0; i < 9; ++i) ssum += __expf(ai[i] + tr[i * 9 + jj] - m);
    al = em[t * 9 + jj] + m + __logf(ssum);
  }
  float v = (l < 9) ? (al + etrans[l]) : -3.0e38f;
  float m2 = v;
  #pragma unroll
  for (int off = 32; off; off >>= 1) m2 = fmaxf(m2, __shfl_xor(m2, off, 64));
  float ex = (l < 9) ? __expf(v - m2) : 0.f;
  #pragma unroll
  for (int off = 32; off; off >>= 1) ex += __shfl_xor(ex, off, 64);
  const float logZ = m2 + __logf(ex);
  if (l == 0) atomicAdd(out, -(score - logZ) * (1.0f / 64.0f));
}

extern "C" void kernel_launch(void* const* d_in, const int* in_sizes, int n_in,
                              void* d_out, int out_size, void* d_ws, size_t ws_size,
                              hipStream_t stream) {
  (void)in_sizes; (void)n_in; (void)out_size; (void)ws_size;
  const int*   sent = (const int*)d_in[0];
  const int*   tags = (const int*)d_in[1];
  const float* emb  = (const float*)d_in[3];
  const float* wihf = (const float*)d_in[4];
  const float* whhf = (const float*)d_in[5];
  const float* bihf = (const float*)d_in[6];
  const float* bhhf = (const float*)d_in[7];
  const float* wihb = (const float*)d_in[8];
  const float* whhb = (const float*)d_in[9];
  const float* bihb = (const float*)d_in[10];
  const float* bhhb = (const float*)d_in[11];
  const float* wout = (const float*)d_in[12];
  const float* bout = (const float*)d_in[13];
  const float* strn = (const float*)d_in[14];
  const float* etrn = (const float*)d_in[15];
  const float* trn  = (const float*)d_in[16];

  char* ws = (char*)d_ws;
  float*   biasb = (float*)(ws + OFF_BIAS);
  uint8_t* wfrag = (uint8_t*)(ws + OFF_WFRAG);
  u16*     hhist = (u16*)(ws + OFF_HHIST);
  float*   feats = (float*)(ws + OFF_FEATS);
  u16*     xgf   = (u16*)(ws + OFF_XG);
  u16*     xbf   = (u16*)(ws + OFF_XBF);
  u16*     wbf   = (u16*)(ws + OFF_WBF);
  int*     flags = (int*)(ws + OFF_FLAGS);
  float*   out   = (float*)d_out;

  hipMemsetAsync(d_out, 0, sizeof(float), stream);
  hipMemsetAsync(flags, 0, 2048, stream);

  hipFuncSetAttribute(reinterpret_cast<const void*>(fused_xg_lstm_kernel),
                      hipFuncAttributeMaxDynamicSharedMemorySize, 70656);

  bias_kernel<<<8, 256, 0, stream>>>(bihf, bhhf, bihb, bhhb, biasb);
  pack_kernel<<<4352, 256, 0, stream>>>(sent, emb, wihf, wihb, xbf, wbf);
  wfrag_prep_kernel<<<128, 256, 0, stream>>>(whhf, whhb, wfrag);
  fused_xg_lstm_kernel<<<4128, 512, 70656, stream>>>(xbf, wbf, biasb, xgf,
                                                     wfrag, hhist, flags);
  proj_kernel<<<1024, 256, 0, stream>>>(hhist, wout, bout, feats);
  crf_kernel<<<64, 64, 0, stream>>>(feats, tags, strn, etrn, trn, out);
}